// Round 3
// baseline (139.497 us; speedup 1.0000x reference)
//
#include <hip/hip_runtime.h>
#include <stdint.h>

typedef __attribute__((ext_vector_type(8))) short short8;
typedef __attribute__((ext_vector_type(4))) float floatx4;

#define MFMA(a, b, c) __builtin_amdgcn_mfma_f32_16x16x32_bf16(a, b, c, 0, 0, 0)

union Frag { uint32_t u[4]; short8 s; };

// split fp32 x into hi=bf16(trunc), lo=bf16(trunc of exact residual); pack two
// values' bf16 halves into one dword (a -> low16, b -> high16).
// v_perm_b32: sel bytes 0-3 pick from src1, 4-7 from src0.
__device__ __forceinline__ void packsplit(float a, float b, uint32_t& hi, uint32_t& lo) {
    uint32_t ua = __float_as_uint(a), ub = __float_as_uint(b);
    uint32_t ha = ua & 0xFFFF0000u, hb = ub & 0xFFFF0000u;
    float ra = a - __uint_as_float(ha);   // exact in fp32
    float rb = b - __uint_as_float(hb);
    hi = __builtin_amdgcn_perm(ub, ua, 0x07060302u);  // {ub.hi16 : ua.hi16}
    lo = __builtin_amdgcn_perm(__float_as_uint(rb), __float_as_uint(ra), 0x07060302u);
}

__device__ __forceinline__ float fexp2(float x) {
#if __has_builtin(__builtin_amdgcn_exp2f)
    return __builtin_amdgcn_exp2f(x);     // v_exp_f32 = 2^x
#else
    return exp2f(x);
#endif
}

// Raw barrier: LDS-visibility only. Global loads stay IN FLIGHT across it
// (unlike __syncthreads, which drains vmcnt(0) and re-exposes HBM latency).
__device__ __forceinline__ void bar_lds() {
    asm volatile("s_waitcnt lgkmcnt(0)" ::: "memory");
    __builtin_amdgcn_s_barrier();
    __builtin_amdgcn_sched_barrier(0);
}

// LDS dword map, per group g (base gb = g*9216):
//   K hi  gb+0..2304      (64 m-rows x 36 dw)   -> reused as P hi after QK
//   K lo  gb+2304..4608                          -> reused as P lo
//   V hi  gb+4608..6912   (64 d-rows x 36 dw, swizzled cols)
//   V lo  gb+6912..9216
// Epilogue (inside group-1 region): O1 fp32 [64][65] @9216, m1 @13376, l1 @13440.

__global__ __launch_bounds__(512, 4)
void msmha_flash(const float* __restrict__ qg, const float* __restrict__ kg,
                 const float* __restrict__ vg, const float* __restrict__ Dg,
                 const float* __restrict__ m1w, const float* __restrict__ m1b,
                 const float* __restrict__ m2w, const float* __restrict__ m2b,
                 float* __restrict__ outg) {
    __shared__ __align__(16) uint32_t sm[18432];   // 72 KiB
    __shared__ __align__(16) float4 wlds[16];

    const int tid   = threadIdx.x;
    const int w     = tid >> 6;
    const int group = w >> 2;          // 0: m in [0,256), 1: m in [256,512)
    const int gw    = w & 3;           // t-tile within group (16 t-rows)
    const int lane  = tid & 63;
    const int col   = lane & 15;
    const int quad  = lane >> 4;
    const int gtid  = tid & 255;

    const int bid = blockIdx.x;
    const int wgT = bid & 7;           // 8 T-tiles of 64
    const int bh  = bid >> 3;
    const int h   = bh & 15;
    const int b   = bh >> 4;
    const int t0g = wgT * 64;

    const size_t base = (size_t)bh * 512 * 64;
    const float LOG2E = 1.4426950408889634f;

    // Channel weights, pre-scaled (log2e folded; 1/8 dot scale folded into .x)
    if (tid < 16) {
        const float w1d = m1w[h * 32 + tid];
        const float w1s = m1w[h * 32 + 16 + tid];
        const float b1  = m1b[h * 16 + tid];
        const float w2  = m2w[h * 16 + tid];
        wlds[tid] = make_float4(w1d * (0.125f * LOG2E), w1s * LOG2E, b1 * LOG2E, 0.5f * w2);
    }

    // staging indices (per 256-thread group)
    const int ml0  = gtid >> 4;                 // K rows ml0 + it*16
    const int k4   = gtid & 15;
    const int dgrp = gtid & 15;                 // V d-group (4 d per thread)
    const int m4   = gtid >> 4;                 // V m-group (4 m per thread)
    const int cpV  = (2 * m4 + 8 * ((dgrp >> 1) & 3)) & 31;   // V write swizzle
    const int rsel = col >> 3;

    const int gb = group * 9216;
    uint32_t* KH = sm + gb;
    uint32_t* KL = sm + gb + 2304;
    uint32_t* VH = sm + gb + 4608;
    uint32_t* VL = sm + gb + 6912;

    const int moff = group * 256;
    const float* kc = kg + base + (size_t)moff * 64;
    const float* vc = vg + base + (size_t)moff * 64;
    const float* Dc = Dg + ((size_t)b * 512 + t0g + gw * 16 + col) * 512 + moff + quad * 4;

    // ---------- prologue: issue chunk-0 K/D/V loads, then Q ----------
    float4 kp[2][4], vp[2][4], dp[2][4];
#pragma unroll
    for (int it = 0; it < 4; ++it)
        kp[0][it] = *(const float4*)(kc + (size_t)(ml0 + it * 16) * 64 + k4 * 4);
#pragma unroll
    for (int mt = 0; mt < 4; ++mt)
        dp[0][mt] = *(const float4*)(Dc + mt * 16);
#pragma unroll
    for (int i = 0; i < 4; ++i)
        vp[0][i] = *(const float4*)(vc + (size_t)(4 * m4 + i) * 64 + dgrp * 4);

    // Linear half of relu split: sum_c w2*relu(h) = sum_c (w2/2)h + (w2/2)|h|
    // (scalar-ish prologue; also covers the chunk-0 load latency)
    float sA = 0.f, sB = 0.f, sC = 0.f;
#pragma unroll 1
    for (int c = 0; c < 16; ++c) {
        const float w2 = m2w[h * 16 + c];
        sA = fmaf(w2, m1w[h * 32 + c], sA);
        sB = fmaf(w2, m1w[h * 32 + 16 + c], sB);
        sC = fmaf(w2, m1b[h * 16 + c], sC);
    }
    const float Ac = sA * (0.0625f * LOG2E);
    const float Bc = sB * (0.5f * LOG2E);
    const float Cc = fmaf(0.5f, sC, m2b[h]) * LOG2E;

    // Q fragments (B-operand: lane col = t-row, k = quad*8+j), split bf16
    Frag qh[2], ql[2];
    {
        const float* qrow = qg + base + (size_t)(t0g + gw * 16 + col) * 64;
#pragma unroll
        for (int ks = 0; ks < 2; ++ks) {
            const float4 f0 = *(const float4*)(qrow + ks * 32 + quad * 8);
            const float4 f1 = *(const float4*)(qrow + ks * 32 + quad * 8 + 4);
            packsplit(f0.x, f0.y, qh[ks].u[0], ql[ks].u[0]);
            packsplit(f0.z, f0.w, qh[ks].u[1], ql[ks].u[1]);
            packsplit(f1.x, f1.y, qh[ks].u[2], ql[ks].u[2]);
            packsplit(f1.z, f1.w, qh[ks].u[3], ql[ks].u[3]);
        }
    }

    float run_m = -3.0e38f, run_l = 0.f;
    floatx4 oacc[4];
#pragma unroll
    for (int dt = 0; dt < 4; ++dt) oacc[dt] = floatx4{0.f, 0.f, 0.f, 0.f};

#pragma unroll
    for (int mc = 0; mc < 4; ++mc) {
        const int cur = mc & 1, nxt = cur ^ 1;

        // pack K[mc] -> LDS (counted vmcnt wait on kp[cur] only)
#pragma unroll
        for (int it = 0; it < 4; ++it) {
            uint32_t h0, l0, h1, l1;
            packsplit(kp[cur][it].x, kp[cur][it].y, h0, l0);
            packsplit(kp[cur][it].z, kp[cur][it].w, h1, l1);
            const int ml = ml0 + it * 16;
            *(uint2*)(KH + ml * 36 + 2 * k4) = make_uint2(h0, h1);
            *(uint2*)(KL + ml * 36 + 2 * k4) = make_uint2(l0, l1);
        }
        // prefetch K[mc+1]: stays in flight across the barriers below
        if (mc < 3) {
            const float* kn = kc + (size_t)(mc + 1) * 64 * 64;
#pragma unroll
            for (int it = 0; it < 4; ++it)
                kp[nxt][it] = *(const float4*)(kn + (size_t)(ml0 + it * 16) * 64 + k4 * 4);
        }
        bar_lds();                             // K staged (LDS only — no vmcnt drain)

        // S^T = K·Q^T via split bf16
        floatx4 sc[4];
        __builtin_amdgcn_s_setprio(1);
#pragma unroll
        for (int mt = 0; mt < 4; ++mt) {
            floatx4 acc = {0.f, 0.f, 0.f, 0.f};
#pragma unroll
            for (int ks = 0; ks < 2; ++ks) {
                const int ro = (mt * 16 + col) * 36 + 16 * ks + 4 * quad;
                Frag ah, al;
                ah.s = *(const short8*)(KH + ro);
                al.s = *(const short8*)(KL + ro);
                acc = MFMA(ah.s, qh[ks].s, acc);
                acc = MFMA(ah.s, ql[ks].s, acc);
                acc = MFMA(al.s, qh[ks].s, acc);
            }
            sc[mt] = acc;   // raw dot
        }
        __builtin_amdgcn_s_setprio(0);

        // fused MLP: mix = Cc + Bc*D + Ac*dot + sum_c (w2/2)|h_c|
        float dvf[16];
#pragma unroll
        for (int mt = 0; mt < 4; ++mt) {
            dvf[mt * 4 + 0] = dp[cur][mt].x; dvf[mt * 4 + 1] = dp[cur][mt].y;
            dvf[mt * 4 + 2] = dp[cur][mt].z; dvf[mt * 4 + 3] = dp[cur][mt].w;
        }
        float mix[16];
#pragma unroll
        for (int e = 0; e < 16; ++e) mix[e] = fmaf(dvf[e], Bc, Cc);
#pragma unroll 4
        for (int c = 0; c < 16; ++c) {
            const float4 wv = wlds[c];
#pragma unroll
            for (int mt = 0; mt < 4; ++mt)
#pragma unroll
                for (int r = 0; r < 4; ++r) {
                    const float hh = fmaf(sc[mt][r], wv.x, fmaf(dvf[mt * 4 + r], wv.y, wv.z));
                    mix[mt * 4 + r] = fmaf(fabsf(hh), wv.w, mix[mt * 4 + r]);
                }
        }
#pragma unroll
        for (int mt = 0; mt < 4; ++mt)
#pragma unroll
            for (int r = 0; r < 4; ++r)
                sc[mt][r] = fmaf(sc[mt][r], Ac, mix[mt * 4 + r]);   // log2-domain score

        // prefetch D[mc+1] (dp[cur] now dead; cover = PV + next K-pack + next QK)
        if (mc < 3) {
#pragma unroll
            for (int mt = 0; mt < 4; ++mt)
                dp[nxt][mt] = *(const float4*)(Dc + (mc + 1) * 64 + mt * 16);
        }

        // pack V[mc] -> LDS (swizzled); then prefetch V[mc+1]
#pragma unroll
        for (int jj = 0; jj < 4; ++jj) {
            uint32_t h0, l0, h1, l1;
            packsplit(((const float*)&vp[cur][0])[jj], ((const float*)&vp[cur][1])[jj], h0, l0);
            packsplit(((const float*)&vp[cur][2])[jj], ((const float*)&vp[cur][3])[jj], h1, l1);
            const int d = 4 * dgrp + jj;
            *(uint2*)(VH + d * 36 + cpV) = make_uint2(h0, h1);
            *(uint2*)(VL + d * 36 + cpV) = make_uint2(l0, l1);
        }
        if (mc < 3) {
            const float* vn = vc + (size_t)(mc + 1) * 64 * 64;
#pragma unroll
            for (int i = 0; i < 4; ++i)
                vp[nxt][i] = *(const float4*)(vn + (size_t)(4 * m4 + i) * 64 + dgrp * 4);
        }

        // online softmax update (per t=col)
        float cmx = -3.0e38f;
#pragma unroll
        for (int mt = 0; mt < 4; ++mt)
#pragma unroll
            for (int r = 0; r < 4; ++r) cmx = fmaxf(cmx, sc[mt][r]);
        cmx = fmaxf(cmx, __shfl_xor(cmx, 16, 64));
        cmx = fmaxf(cmx, __shfl_xor(cmx, 32, 64));
        const float nm    = fmaxf(run_m, cmx);
        const float scale = fexp2(run_m - nm);
        float csum = 0.f;
#pragma unroll
        for (int mt = 0; mt < 4; ++mt)
#pragma unroll
            for (int r = 0; r < 4; ++r) {
                const float p = fexp2(sc[mt][r] - nm);
                sc[mt][r] = p;
                csum += p;
            }
        csum += __shfl_xor(csum, 16, 64);
        csum += __shfl_xor(csum, 32, 64);
        run_l = fmaf(run_l, scale, csum);
        run_m = nm;
        float sOT[4];
#pragma unroll
        for (int r = 0; r < 4; ++r) sOT[r] = __shfl(scale, quad * 4 + r, 64);
#pragma unroll
        for (int dt = 0; dt < 4; ++dt)
#pragma unroll
            for (int r = 0; r < 4; ++r) oacc[dt][r] *= sOT[r];

        bar_lds();                             // QK K-reads done; V visible

        // P -> LDS (reuses K region; wave-private rows)
        const int prow = (gw * 16 + col) * 36;
#pragma unroll
        for (int mt = 0; mt < 4; ++mt) {
            uint32_t h0, l0, h1, l1;
            packsplit(sc[mt][0], sc[mt][1], h0, l0);
            packsplit(sc[mt][2], sc[mt][3], h1, l1);
            *(uint2*)(KH + prow + mt * 8 + 2 * quad) = make_uint2(h0, h1);
            *(uint2*)(KL + prow + mt * 8 + 2 * quad) = make_uint2(l0, l1);
        }

        // O += P·V
        __builtin_amdgcn_s_setprio(1);
#pragma unroll
        for (int ks = 0; ks < 2; ++ks) {
            const int po = prow + 16 * ks + 4 * quad;
            Frag pah, pal;
            pah.s = *(const short8*)(KH + po);
            pal.s = *(const short8*)(KL + po);
#pragma unroll
            for (int dt = 0; dt < 4; ++dt) {
                const int cbd = ((16 * ks + 4 * quad) + 8 * ((2 * dt + rsel) & 3)) & 31;
                const int vo = (dt * 16 + col) * 36 + cbd;
                Frag bhv, blv;
                bhv.s = *(const short8*)(VH + vo);
                blv.s = *(const short8*)(VL + vo);
                oacc[dt] = MFMA(pah.s, bhv.s, oacc[dt]);
                oacc[dt] = MFMA(pah.s, blv.s, oacc[dt]);
                oacc[dt] = MFMA(pal.s, bhv.s, oacc[dt]);
            }
        }
        __builtin_amdgcn_s_setprio(0);

        bar_lds();                             // PV reads done before next staging
    }

    // ================= combine the two m-halves, store =================
    const float rv_part = run_l;   // keep names alive for clarity
    float* smf = (float*)sm;
    if (group == 1) {
        if (quad == 0) {
            smf[13376 + gw * 16 + col] = run_m;
            smf[13440 + gw * 16 + col] = rv_part;
        }
        const int t = gw * 16 + quad * 4;
#pragma unroll
        for (int dt = 0; dt < 4; ++dt)
#pragma unroll
            for (int r = 0; r < 4; ++r)
                smf[9216 + (t + r) * 65 + dt * 16 + col] = oacc[dt][r];
    }
    bar_lds();
    if (group == 0) {
        const float m1c = smf[13376 + gw * 16 + col];
        const float l1c = smf[13440 + gw * 16 + col];
        const float M   = fmaxf(run_m, m1c);
        const float s0  = fexp2(run_m - M);
        const float s1  = fexp2(m1c - M);
        const float rdn = 1.f / fmaf(run_l, s0, l1c * s1);
        float s0T[4], s1T[4], rdT[4];
#pragma unroll
        for (int r = 0; r < 4; ++r) {
            s0T[r] = __shfl(s0, quad * 4 + r, 64);
            s1T[r] = __shfl(s1, quad * 4 + r, 64);
            rdT[r] = __shfl(rdn, quad * 4 + r, 64);
        }
        const int t = gw * 16 + quad * 4;
        const size_t obase = ((size_t)b * 512 + t0g + t) * 1024 + h * 64 + col;
#pragma unroll
        for (int dt = 0; dt < 4; ++dt)
#pragma unroll
            for (int r = 0; r < 4; ++r) {
                const float o1 = smf[9216 + (t + r) * 65 + dt * 16 + col];
                outg[obase + (size_t)r * 1024 + dt * 16] =
                    fmaf(oacc[dt][r], s0T[r], o1 * s1T[r]) * rdT[r];
            }
    }
}

extern "C" void kernel_launch(void* const* d_in, const int* in_sizes, int n_in,
                              void* d_out, int out_size, void* d_ws, size_t ws_size,
                              hipStream_t stream) {
    const float* q   = (const float*)d_in[0];
    const float* k   = (const float*)d_in[1];
    const float* v   = (const float*)d_in[2];
    const float* dtm = (const float*)d_in[3];
    const float* m1w = (const float*)d_in[4];
    const float* m1b = (const float*)d_in[5];
    const float* m2w = (const float*)d_in[6];
    const float* m2b = (const float*)d_in[7];
    float* out = (float*)d_out;

    dim3 grid(4 * 16 * 8);   // 512 workgroups: (b,h) x 8 T-tiles
    dim3 block(512);         // 8 waves: 2 m-groups x 4 t-tiles
    msmha_flash<<<grid, block, 0, stream>>>(q, k, v, dtm, m1w, m1b, m2w, m2b, out);
}

// Round 5
// 135.095 us; speedup vs baseline: 1.0326x; 1.0326x over previous
//
#include <hip/hip_runtime.h>
#include <stdint.h>

typedef __attribute__((ext_vector_type(8))) short short8;
typedef __attribute__((ext_vector_type(4))) float floatx4;

#define MFMA(a, b, c) __builtin_amdgcn_mfma_f32_16x16x32_bf16(a, b, c, 0, 0, 0)

union Frag { uint32_t u[4]; short8 s; };

// split fp32 x into hi=bf16(trunc), lo=bf16(trunc of exact residual); pack two
// values' bf16 halves into one dword (a -> low16, b -> high16).
__device__ __forceinline__ void packsplit(float a, float b, uint32_t& hi, uint32_t& lo) {
    uint32_t ua = __float_as_uint(a), ub = __float_as_uint(b);
    uint32_t ha = ua & 0xFFFF0000u, hb = ub & 0xFFFF0000u;
    float ra = a - __uint_as_float(ha);   // exact in fp32
    float rb = b - __uint_as_float(hb);
    hi = __builtin_amdgcn_perm(ub, ua, 0x07060302u);  // {ub.hi16 : ua.hi16}
    lo = __builtin_amdgcn_perm(__float_as_uint(rb), __float_as_uint(ra), 0x07060302u);
}

__device__ __forceinline__ float fexp2(float x) {
#if __has_builtin(__builtin_amdgcn_exp2f)
    return __builtin_amdgcn_exp2f(x);     // v_exp_f32 = 2^x
#else
    return exp2f(x);
#endif
}

// Raw barrier: LDS-visibility only. Global loads stay IN FLIGHT across it
// (unlike __syncthreads, which drains vmcnt(0) and re-exposes HBM latency).
__device__ __forceinline__ void bar_lds() {
    asm volatile("s_waitcnt lgkmcnt(0)" ::: "memory");
    __builtin_amdgcn_s_barrier();
    __builtin_amdgcn_sched_barrier(0);
}

// LDS dword map, per group g (base gb = g*9216):
//   K hi  gb+0..2304      (64 m-rows x 36 dw)   -> reused as P hi after QK
//   K lo  gb+2304..4608                          -> reused as P lo
//   V hi  gb+4608..6912   (64 d-rows x 36 dw, swizzled cols)
//   V lo  gb+6912..9216
// Epilogue (inside group-1 region): O1 fp32 [64][65] @9216, m1 @13376, l1 @13440.

__attribute__((amdgpu_waves_per_eu(4, 4)))   // pin 4 waves/EU -> full 128-VGPR budget
__global__ __launch_bounds__(512)
void msmha_flash(const float* __restrict__ qg, const float* __restrict__ kg,
                 const float* __restrict__ vg, const float* __restrict__ Dg,
                 const float* __restrict__ m1w, const float* __restrict__ m1b,
                 const float* __restrict__ m2w, const float* __restrict__ m2b,
                 float* __restrict__ outg) {
    __shared__ __align__(16) uint32_t sm[18432];   // 72 KiB
    __shared__ __align__(16) float4 wlds[16];

    const int tid   = threadIdx.x;
    const int w     = tid >> 6;
    const int group = w >> 2;          // 0: m in [0,256), 1: m in [256,512)
    const int gw    = w & 3;           // t-tile within group (16 t-rows)
    const int lane  = tid & 63;
    const int col   = lane & 15;
    const int quad  = lane >> 4;
    const int gtid  = tid & 255;

    // XCD-aware remap: the 8 T-tiles of one (b,h) share K/V; keep them on ONE
    // XCD's L2 (dispatch round-robins bid%8 across XCDs).
    const int bid = blockIdx.x;
    const int wgT = bid >> 6;          // 8 T-tiles of 64
    const int bh  = bid & 63;
    const int h   = bh & 15;
    const int b   = bh >> 4;
    const int t0g = wgT * 64;

    const size_t base = (size_t)bh * 512 * 64;
    const float LOG2E = 1.4426950408889634f;

    // Channel weights, pre-scaled (log2e folded; 1/8 dot scale folded into .x)
    if (tid < 16) {
        const float w1d = m1w[h * 32 + tid];
        const float w1s = m1w[h * 32 + 16 + tid];
        const float b1  = m1b[h * 16 + tid];
        const float w2  = m2w[h * 16 + tid];
        wlds[tid] = make_float4(w1d * (0.125f * LOG2E), w1s * LOG2E, b1 * LOG2E, 0.5f * w2);
    }

    // staging indices (per 256-thread group)
    const int ml0  = gtid >> 4;                 // K rows ml0 + it*16
    const int k4   = gtid & 15;
    const int dgrp = gtid & 15;                 // V d-group (4 d per thread)
    const int m4   = gtid >> 4;                 // V m-group (4 m per thread)
    const int cpV  = (2 * m4 + 8 * ((dgrp >> 1) & 3)) & 31;   // V write swizzle
    const int rsel = col >> 3;

    const int gb = group * 9216;
    uint32_t* KH = sm + gb;
    uint32_t* KL = sm + gb + 2304;
    uint32_t* VH = sm + gb + 4608;
    uint32_t* VL = sm + gb + 6912;

    const int moff = group * 256;
    const float* kc = kg + base + (size_t)moff * 64;
    const float* vc = vg + base + (size_t)moff * 64;
    const float* Dc = Dg + ((size_t)b * 512 + t0g + gw * 16 + col) * 512 + moff + quad * 4;

    // ---------- prologue: issue chunk-0 K/D/V loads (single buffers) ----------
    float4 kp[4], vp[4], dp[4];
#pragma unroll
    for (int it = 0; it < 4; ++it)
        kp[it] = *(const float4*)(kc + (size_t)(ml0 + it * 16) * 64 + k4 * 4);
#pragma unroll
    for (int mt = 0; mt < 4; ++mt)
        dp[mt] = *(const float4*)(Dc + mt * 16);
#pragma unroll
    for (int i = 0; i < 4; ++i)
        vp[i] = *(const float4*)(vc + (size_t)(4 * m4 + i) * 64 + dgrp * 4);

    // Linear half of relu split: sum_c w2*relu(h) = sum_c (w2/2)h + (w2/2)|h|
    // (scalar prologue also covers chunk-0 load latency)
    float sA = 0.f, sB = 0.f, sC = 0.f;
#pragma unroll 1
    for (int c = 0; c < 16; ++c) {
        const float w2 = m2w[h * 16 + c];
        sA = fmaf(w2, m1w[h * 32 + c], sA);
        sB = fmaf(w2, m1w[h * 32 + 16 + c], sB);
        sC = fmaf(w2, m1b[h * 16 + c], sC);
    }
    const float Ac = sA * (0.0625f * LOG2E);
    const float Bc = sB * (0.5f * LOG2E);
    const float Cc = fmaf(0.5f, sC, m2b[h]) * LOG2E;

    // Q fragments (B-operand: lane col = t-row, k = quad*8+j), split bf16
    Frag qh[2], ql[2];
    {
        const float* qrow = qg + base + (size_t)(t0g + gw * 16 + col) * 64;
#pragma unroll
        for (int ks = 0; ks < 2; ++ks) {
            const float4 f0 = *(const float4*)(qrow + ks * 32 + quad * 8);
            const float4 f1 = *(const float4*)(qrow + ks * 32 + quad * 8 + 4);
            packsplit(f0.x, f0.y, qh[ks].u[0], ql[ks].u[0]);
            packsplit(f0.z, f0.w, qh[ks].u[1], ql[ks].u[1]);
            packsplit(f1.x, f1.y, qh[ks].u[2], ql[ks].u[2]);
            packsplit(f1.z, f1.w, qh[ks].u[3], ql[ks].u[3]);
        }
    }

    float run_m = -3.0e38f, run_l = 0.f;
    floatx4 oacc[4];
#pragma unroll
    for (int dt = 0; dt < 4; ++dt) oacc[dt] = floatx4{0.f, 0.f, 0.f, 0.f};

#pragma unroll
    for (int mc = 0; mc < 4; ++mc) {
        // pack K[mc] -> LDS (counted vmcnt wait on kp only; D/V stay in flight)
#pragma unroll
        for (int it = 0; it < 4; ++it) {
            uint32_t h0, l0, h1, l1;
            packsplit(kp[it].x, kp[it].y, h0, l0);
            packsplit(kp[it].z, kp[it].w, h1, l1);
            const int ml = ml0 + it * 16;
            *(uint2*)(KH + ml * 36 + 2 * k4) = make_uint2(h0, h1);
            *(uint2*)(KL + ml * 36 + 2 * k4) = make_uint2(l0, l1);
        }
        // prefetch K[mc+1] into the SAME buffer (just consumed) — in flight
        // across the barriers below, landing by next chunk's K-pack.
        if (mc < 3) {
            const float* kn = kc + (size_t)(mc + 1) * 64 * 64;
#pragma unroll
            for (int it = 0; it < 4; ++it)
                kp[it] = *(const float4*)(kn + (size_t)(ml0 + it * 16) * 64 + k4 * 4);
        }
        bar_lds();                             // K staged (LDS only — no vmcnt drain)

        // S^T = K·Q^T via split bf16
        floatx4 sc[4];
        __builtin_amdgcn_s_setprio(1);
#pragma unroll
        for (int mt = 0; mt < 4; ++mt) {
            floatx4 acc = {0.f, 0.f, 0.f, 0.f};
#pragma unroll
            for (int ks = 0; ks < 2; ++ks) {
                const int ro = (mt * 16 + col) * 36 + 16 * ks + 4 * quad;
                Frag ah, al;
                ah.s = *(const short8*)(KH + ro);
                al.s = *(const short8*)(KL + ro);
                acc = MFMA(ah.s, qh[ks].s, acc);
                acc = MFMA(ah.s, ql[ks].s, acc);
                acc = MFMA(al.s, qh[ks].s, acc);
            }
            sc[mt] = acc;   // raw dot
        }
        __builtin_amdgcn_s_setprio(0);

        // fused MLP: mix = Cc + Bc*D + Ac*dot + sum_c (w2/2)|h_c|
        float dvf[16];
#pragma unroll
        for (int mt = 0; mt < 4; ++mt) {
            dvf[mt * 4 + 0] = dp[mt].x; dvf[mt * 4 + 1] = dp[mt].y;
            dvf[mt * 4 + 2] = dp[mt].z; dvf[mt * 4 + 3] = dp[mt].w;
        }
        float mix[16];
#pragma unroll
        for (int e = 0; e < 16; ++e) mix[e] = fmaf(dvf[e], Bc, Cc);
#pragma unroll 4
        for (int c = 0; c < 16; ++c) {
            const float4 wv = wlds[c];
#pragma unroll
            for (int mt = 0; mt < 4; ++mt)
#pragma unroll
                for (int r = 0; r < 4; ++r) {
                    const float hh = fmaf(sc[mt][r], wv.x, fmaf(dvf[mt * 4 + r], wv.y, wv.z));
                    mix[mt * 4 + r] = fmaf(fabsf(hh), wv.w, mix[mt * 4 + r]);
                }
        }
#pragma unroll
        for (int mt = 0; mt < 4; ++mt)
#pragma unroll
            for (int r = 0; r < 4; ++r)
                sc[mt][r] = fmaf(sc[mt][r], Ac, mix[mt * 4 + r]);   // log2-domain score

        // prefetch D[mc+1] (dp now dead; cover = rest of chunk + next K-pack + QK)
        if (mc < 3) {
#pragma unroll
            for (int mt = 0; mt < 4; ++mt)
                dp[mt] = *(const float4*)(Dc + (mc + 1) * 64 + mt * 16);
        }

        // pack V[mc] -> LDS (swizzled); then prefetch V[mc+1]
#pragma unroll
        for (int jj = 0; jj < 4; ++jj) {
            uint32_t h0, l0, h1, l1;
            packsplit(((const float*)&vp[0])[jj], ((const float*)&vp[1])[jj], h0, l0);
            packsplit(((const float*)&vp[2])[jj], ((const float*)&vp[3])[jj], h1, l1);
            const int d = 4 * dgrp + jj;
            *(uint2*)(VH + d * 36 + cpV) = make_uint2(h0, h1);
            *(uint2*)(VL + d * 36 + cpV) = make_uint2(l0, l1);
        }
        if (mc < 3) {
            const float* vn = vc + (size_t)(mc + 1) * 64 * 64;
#pragma unroll
            for (int i = 0; i < 4; ++i)
                vp[i] = *(const float4*)(vn + (size_t)(4 * m4 + i) * 64 + dgrp * 4);
        }

        // online softmax update (per t=col)
        float cmx = -3.0e38f;
#pragma unroll
        for (int mt = 0; mt < 4; ++mt)
#pragma unroll
            for (int r = 0; r < 4; ++r) cmx = fmaxf(cmx, sc[mt][r]);
        cmx = fmaxf(cmx, __shfl_xor(cmx, 16, 64));
        cmx = fmaxf(cmx, __shfl_xor(cmx, 32, 64));
        const float nm    = fmaxf(run_m, cmx);
        const float scale = fexp2(run_m - nm);
        float csum = 0.f;
#pragma unroll
        for (int mt = 0; mt < 4; ++mt)
#pragma unroll
            for (int r = 0; r < 4; ++r) {
                const float p = fexp2(sc[mt][r] - nm);
                sc[mt][r] = p;
                csum += p;
            }
        csum += __shfl_xor(csum, 16, 64);
        csum += __shfl_xor(csum, 32, 64);
        run_l = fmaf(run_l, scale, csum);
        run_m = nm;
        float sOT[4];
#pragma unroll
        for (int r = 0; r < 4; ++r) sOT[r] = __shfl(scale, quad * 4 + r, 64);
#pragma unroll
        for (int dt = 0; dt < 4; ++dt)
#pragma unroll
            for (int r = 0; r < 4; ++r) oacc[dt][r] *= sOT[r];

        bar_lds();                             // QK K-reads done; V visible

        // P -> LDS (reuses K region; wave-private rows, no barrier needed)
        const int prow = (gw * 16 + col) * 36;
#pragma unroll
        for (int mt = 0; mt < 4; ++mt) {
            uint32_t h0, l0, h1, l1;
            packsplit(sc[mt][0], sc[mt][1], h0, l0);
            packsplit(sc[mt][2], sc[mt][3], h1, l1);
            *(uint2*)(KH + prow + mt * 8 + 2 * quad) = make_uint2(h0, h1);
            *(uint2*)(KL + prow + mt * 8 + 2 * quad) = make_uint2(l0, l1);
        }

        // O += P·V
        __builtin_amdgcn_s_setprio(1);
#pragma unroll
        for (int ks = 0; ks < 2; ++ks) {
            const int po = prow + 16 * ks + 4 * quad;
            Frag pah, pal;
            pah.s = *(const short8*)(KH + po);
            pal.s = *(const short8*)(KL + po);
#pragma unroll
            for (int dt = 0; dt < 4; ++dt) {
                const int cbd = ((16 * ks + 4 * quad) + 8 * ((2 * dt + rsel) & 3)) & 31;
                const int vo = (dt * 16 + col) * 36 + cbd;
                Frag bhv, blv;
                bhv.s = *(const short8*)(VH + vo);
                blv.s = *(const short8*)(VL + vo);
                oacc[dt] = MFMA(pah.s, bhv.s, oacc[dt]);
                oacc[dt] = MFMA(pah.s, blv.s, oacc[dt]);
                oacc[dt] = MFMA(pal.s, bhv.s, oacc[dt]);
            }
        }
        __builtin_amdgcn_s_setprio(0);

        bar_lds();                             // PV reads done before next staging
    }

    // ================= combine the two m-halves, store =================
    float* smf = (float*)sm;
    if (group == 1) {
        if (quad == 0) {
            smf[13376 + gw * 16 + col] = run_m;
            smf[13440 + gw * 16 + col] = run_l;
        }
        const int t = gw * 16 + quad * 4;
#pragma unroll
        for (int dt = 0; dt < 4; ++dt)
#pragma unroll
            for (int r = 0; r < 4; ++r)
                smf[9216 + (t + r) * 65 + dt * 16 + col] = oacc[dt][r];
    }
    bar_lds();
    if (group == 0) {
        const float m1c = smf[13376 + gw * 16 + col];
        const float l1c = smf[13440 + gw * 16 + col];
        const float M   = fmaxf(run_m, m1c);
        const float s0  = fexp2(run_m - M);
        const float s1  = fexp2(m1c - M);
        const float rdn = 1.f / fmaf(run_l, s0, l1c * s1);
        float s0T[4], s1T[4], rdT[4];
#pragma unroll
        for (int r = 0; r < 4; ++r) {
            s0T[r] = __shfl(s0, quad * 4 + r, 64);
            s1T[r] = __shfl(s1, quad * 4 + r, 64);
            rdT[r] = __shfl(rdn, quad * 4 + r, 64);
        }
        const int t = gw * 16 + quad * 4;
        const size_t obase = ((size_t)b * 512 + t0g + t) * 1024 + h * 64 + col;
#pragma unroll
        for (int dt = 0; dt < 4; ++dt)
#pragma unroll
            for (int r = 0; r < 4; ++r) {
                const float o1 = smf[9216 + (t + r) * 65 + dt * 16 + col];
                outg[obase + (size_t)r * 1024 + dt * 16] =
                    fmaf(oacc[dt][r], s0T[r], o1 * s1T[r]) * rdT[r];
            }
    }
}

extern "C" void kernel_launch(void* const* d_in, const int* in_sizes, int n_in,
                              void* d_out, int out_size, void* d_ws, size_t ws_size,
                              hipStream_t stream) {
    const float* q   = (const float*)d_in[0];
    const float* k   = (const float*)d_in[1];
    const float* v   = (const float*)d_in[2];
    const float* dtm = (const float*)d_in[3];
    const float* m1w = (const float*)d_in[4];
    const float* m1b = (const float*)d_in[5];
    const float* m2w = (const float*)d_in[6];
    const float* m2b = (const float*)d_in[7];
    float* out = (float*)d_out;

    dim3 grid(4 * 16 * 8);   // 512 workgroups: (b,h) x 8 T-tiles
    dim3 block(512);         // 8 waves: 2 m-groups x 4 t-tiles
    msmha_flash<<<grid, block, 0, stream>>>(q, k, v, dtm, m1w, m1b, m2w, m2b, out);
}